// Round 5
// baseline (616.839 us; speedup 1.0000x reference)
//
#include <hip/hip_runtime.h>
#include <hip/hip_fp16.h>

#define FIN 64
#define HH 64
#define BLK 128
#define CIW 64   // bucket width in ci values for the two-phase scatter

typedef _Float16 h2v __attribute__((ext_vector_type(2)));
typedef _Float16 f16x8 __attribute__((ext_vector_type(8)));
typedef float f32x4 __attribute__((ext_vector_type(4)));
union U4F { uint4 u; f16x8 h; };

__device__ __forceinline__ unsigned pack2(float x, float y) {
    __half2 h = __floats2half2_rn(x, y);     // .x -> low 16 bits
    union { __half2 h; unsigned u; } z; z.h = h;
    return z.u;
}
__device__ __forceinline__ float2 unpack2(unsigned u) {
    union { unsigned u; __half2 h; } z; z.u = u;
    return __half22float2(z.h);
}
__device__ __forceinline__ float fdot2f(unsigned a, unsigned b, float c) {
#if __has_builtin(__builtin_amdgcn_fdot2)
    union { unsigned u; h2v h; } za, zb; za.u = a; zb.u = b;
    return __builtin_amdgcn_fdot2(za.h, zb.h, c, false);
#else
    float2 fa = unpack2(a), fb = unpack2(b);
    return fmaf(fa.x, fb.x, fmaf(fa.y, fb.y, c));
#endif
}

// dot2 layer over own LDS row (32 u32 = 64 f16, XOR-swizzled 16B chunks)
__device__ __forceinline__ void dot2_layer(const unsigned* lds, int t,
        const unsigned* __restrict__ wp, const float* __restrict__ bias, float* h) {
    #pragma unroll
    for (int j = 0; j < 64; ++j) h[j] = bias[j];
    #pragma unroll 1
    for (int c = 0; c < 8; ++c) {
        uint4 hp = *reinterpret_cast<const uint4*>(&lds[(size_t)t * 32 + ((c ^ (t & 7)) << 2)]);
        const unsigned* w0 = wp + (4 * c + 0) * 64;
        const unsigned* w1 = wp + (4 * c + 1) * 64;
        const unsigned* w2 = wp + (4 * c + 2) * 64;
        const unsigned* w3 = wp + (4 * c + 3) * 64;
        #pragma unroll
        for (int j = 0; j < 64; ++j) {
            float a = fdot2f(hp.x, w0[j], h[j]);
            a = fdot2f(hp.y, w1[j], a);
            a = fdot2f(hp.z, w2[j], a);
            h[j] = fdot2f(hp.w, w3[j], a);
        }
    }
}

// ---------------- init: zero agg (d_out) + histogram counters ---------------
__global__ void zero_init(float* agg, int nagg, int* counts, int ncnt) {
    int i = blockIdx.x * blockDim.x + threadIdx.x;
    int stride = gridDim.x * blockDim.x;
    for (int k = i; k < nagg; k += stride) agg[k] = 0.f;
    for (int k = i; k < ncnt; k += stride) counts[k] = 0;
}

// ---- pack weights: W1/W3/W4 dot2 layout; W2 -> MFMA B-fragment layout ------
__global__ void pack_weights(const float* __restrict__ W1, const float* __restrict__ W2,
                             const float* __restrict__ W3, const float* __restrict__ W4,
                             unsigned* wp) {
    int i = blockIdx.x * blockDim.x + threadIdx.x;
    if (i >= 4 * 2048) return;
    int m = i >> 11, r = i & 2047;
    if (m == 1) {
        // B-frag for mfma_f32_16x16x32_f16: lane l, tile (ks,ni), pair p:
        // B[k0..k0+1][col], col = ni*16+(l&15), k0 = ks*32+(l>>4)*8+2p
        int tile = r >> 8;            // ks*4+ni
        int l    = (r >> 2) & 63;
        int p    = r & 3;
        int ni = tile & 3, ks = tile >> 2;
        int col = ni * 16 + (l & 15);
        int k0  = ks * 32 + ((l >> 4) << 3) + 2 * p;
        wp[i] = pack2(W2[k0 * 64 + col], W2[(k0 + 1) * 64 + col]);
    } else {
        int kk = r >> 6, j = r & 63;
        const float* W = (m == 0) ? W1 : (m == 2) ? W3 : W4;
        wp[i] = pack2(W[(2 * kk) * 64 + j], W[(2 * kk + 1) * 64 + j]);
    }
}

// ---------------- pre-pass: pre1[n] = feat[n] @ W1a + b1 (f16, 128B rows) ---
__global__ __launch_bounds__(64, 4) void pre_pass(
    const float* __restrict__ last_features,
    const unsigned* __restrict__ w1p, const float* __restrict__ b1,
    uint4* pre1, int N)
{
    __shared__ unsigned lds[64 * 32];
    int t = threadIdx.x;
    int r = blockIdx.x * 64 + t;
    if (r >= N) return;

    const float4* xr = reinterpret_cast<const float4*>(last_features + (size_t)r * FIN);
    float4 f[16];
    #pragma unroll
    for (int i = 0; i < 16; ++i) f[i] = xr[i];

    #pragma unroll
    for (int c = 0; c < 8; ++c) {
        uint4 o;
        o.x = pack2(f[2 * c].x, f[2 * c].y);
        o.y = pack2(f[2 * c].z, f[2 * c].w);
        o.z = pack2(f[2 * c + 1].x, f[2 * c + 1].y);
        o.w = pack2(f[2 * c + 1].z, f[2 * c + 1].w);
        *reinterpret_cast<uint4*>(&lds[(size_t)t * 32 + ((c ^ (t & 7)) << 2)]) = o;
    }

    float h[64];
    dot2_layer(lds, t, w1p, b1, h);   // pre-activation: NO relu

    uint4* out = pre1 + (size_t)r * 8;
    #pragma unroll
    for (int c = 0; c < 8; ++c) {
        uint4 o;
        o.x = pack2(h[8 * c + 0], h[8 * c + 1]);
        o.y = pack2(h[8 * c + 2], h[8 * c + 3]);
        o.z = pack2(h[8 * c + 4], h[8 * c + 5]);
        o.w = pack2(h[8 * c + 6], h[8 * c + 7]);
        out[c] = o;
    }
}

// ---------------- counting sort: hist + 3-phase parallel scan ---------------
__global__ void hist_kernel(const int* __restrict__ edge, int* counts, int E) {
    int e = blockIdx.x * blockDim.x + threadIdx.x;
    if (e < E) atomicAdd(&counts[edge[e]], 1);
}

__global__ __launch_bounds__(256) void scan_partial(const int* __restrict__ counts,
                                                    int* bsum, int M) {
    __shared__ int s[256];
    int b = blockIdx.x, t = threadIdx.x;
    int i0 = b * 2048 + t * 8;
    int sum = 0;
    if (i0 + 8 <= M) {
        int4 a = *reinterpret_cast<const int4*>(counts + i0);
        int4 c = *reinterpret_cast<const int4*>(counts + i0 + 4);
        sum = a.x + a.y + a.z + a.w + c.x + c.y + c.z + c.w;
    } else {
        for (int j = 0; j < 8; ++j) if (i0 + j < M) sum += counts[i0 + j];
    }
    s[t] = sum;
    __syncthreads();
    for (int o = 128; o > 0; o >>= 1) {
        if (t < o) s[t] += s[t + o];
        __syncthreads();
    }
    if (t == 0) bsum[b] = s[0];
}

__global__ void scan_bsums(int* bsum, int NB) {     // 1 block, 64 threads
    int t = threadIdx.x;
    int carry = 0;
    for (int s0 = 0; s0 < NB; s0 += 64) {
        int idx = s0 + t;
        int v = (idx < NB) ? bsum[idx] : 0;
        for (int o = 1; o < 64; o <<= 1) {
            int n = __shfl_up(v, o);
            if (t >= o) v += n;
        }
        if (idx < NB) bsum[idx] = v + carry;        // inclusive + carry
        carry = __shfl(v + carry, 63);
    }
}

// exclusive per-ci cursor; also emits bucket cursors bc[b] = cursor[b*CIW]
__global__ __launch_bounds__(256) void scan_apply(const int* __restrict__ counts,
                                                  const int* __restrict__ bsum,
                                                  int* cursor, int* bc, int M) {
    __shared__ int s[256];
    int b = blockIdx.x, t = threadIdx.x;
    int i0 = b * 2048 + t * 8;
    int v[8];
    #pragma unroll
    for (int j = 0; j < 8; ++j) v[j] = (i0 + j < M) ? counts[i0 + j] : 0;
    int tot = 0;
    #pragma unroll
    for (int j = 0; j < 8; ++j) { int x = v[j]; v[j] = tot; tot += x; }
    s[t] = tot;
    __syncthreads();
    for (int o = 1; o < 256; o <<= 1) {
        int n = (t >= o) ? s[t - o] : 0;
        __syncthreads();
        s[t] += n;
        __syncthreads();
    }
    int texcl = s[t] - tot;
    int basev = (b > 0 ? bsum[b - 1] : 0) + texcl;
    #pragma unroll
    for (int j = 0; j < 8; ++j) {
        int i = i0 + j;
        if (i < M) {
            int val = basev + v[j];
            cursor[i] = val;
            if ((i & (CIW - 1)) == 0) bc[i / CIW] = val;
        }
    }
}

// ---- phase 1: bin records into 64-ci-wide buckets (sequential-fill writes) -
__global__ void bin_scatter(const int* __restrict__ edge, int* bc, int2* bin, int E) {
    int e = blockIdx.x * blockDim.x + threadIdx.x;
    if (e < E) {
        int ci = edge[e];
        int p = atomicAdd(&bc[ci >> 6], 1);       // CIW = 64
        bin[p] = make_int2(ci, edge[E + e]);
    }
}

// ---- phase 2: block-per-bucket fine sort; LDS cursors, owned dest region ---
__global__ __launch_bounds__(256) void fine_scatter(
    const int2* __restrict__ bin, const int* __restrict__ cursor,
    int2* cl, int M, int E) {
    __shared__ int lcur[CIW];
    int b = blockIdx.x, t = threadIdx.x;
    int lo = b * CIW;
    int hi = min(lo + CIW, M);
    if (t < CIW) lcur[t] = (lo + t < M) ? cursor[lo + t] : E;
    __syncthreads();
    int base = cursor[lo];
    int end = (hi < M) ? cursor[hi] : E;
    for (int p = base + t; p < end; p += 256) {
        int2 r = bin[p];
        int slot = atomicAdd(&lcur[r.x - lo], 1);
        cl[slot] = r;
    }
}

// fallback scatters
__global__ void scatter2(const int* __restrict__ edge, int* cursor, int2* cl, int E) {
    int e = blockIdx.x * blockDim.x + threadIdx.x;
    if (e < E) {
        int ci = edge[e];
        int p = atomicAdd(&cursor[ci], 1);
        cl[p] = make_int2(ci, edge[E + e]);
    }
}
__global__ void scatter_kernel(const int* __restrict__ edge, int* cursor,
                               int* sorted, int E) {
    int e = blockIdx.x * blockDim.x + threadIdx.x;
    if (e < E) {
        int p = atomicAdd(&cursor[edge[e]], 1);
        sorted[p] = e;
    }
}

// ---------------- main edge kernel: layer1 VALU + layer2 MFMA + segmax ------
__global__ __launch_bounds__(64, 2) void edge_mfma(
    const float* __restrict__ last_coors,
    const float* __restrict__ current_coors,
    const int2* __restrict__ cl,
    const uint4* __restrict__ pre1,
    const float* __restrict__ W1,          // rel rows at W1 + 64*64
    const float* __restrict__ b2,
    const unsigned* __restrict__ w2f,      // W2 in B-frag layout
    float* agg, int E)
{
    __shared__ unsigned lds[64 * 32];      // 8 KB: A-stage (swizzled f16), then h2 linear
    __shared__ int cis[64];
    __shared__ int runStart[65];
    int base = blockIdx.x * 64, t = threadIdx.x;
    int nE = min(64, E - base);

    uint4 q[8] = {};
    float r0 = 0.f, r1 = 0.f, r2 = 0.f;
    int ci = -1;
    if (t < nE) {
        int2 e2 = cl[base + t];
        ci = e2.x;
        int li = e2.y;
        const uint4* pr = pre1 + (size_t)li * 8;
        #pragma unroll
        for (int i = 0; i < 8; ++i) q[i] = pr[i];
        r0 = last_coors[3 * li + 0] - current_coors[3 * ci + 0];
        r1 = last_coors[3 * li + 1] - current_coors[3 * ci + 1];
        r2 = last_coors[3 * li + 2] - current_coors[3 * ci + 2];
    }
    cis[t] = ci;

    // h1 = relu(pre + rel @ W1b) -> LDS A-stage, XOR-swizzled 16B chunks
    const float* rw = W1 + 64 * 64;
    #pragma unroll
    for (int c = 0; c < 8; ++c) {
        unsigned qc[4] = {q[c].x, q[c].y, q[c].z, q[c].w};
        unsigned oc[4];
        #pragma unroll
        for (int p = 0; p < 4; ++p) {
            int j0 = 8 * c + 2 * p;
            float2 v = unpack2(qc[p]);
            v.x = fmaf(r0, rw[j0],     fmaf(r1, rw[64 + j0],     fmaf(r2, rw[128 + j0],     v.x)));
            v.y = fmaf(r0, rw[j0 + 1], fmaf(r1, rw[64 + j0 + 1], fmaf(r2, rw[128 + j0 + 1], v.y)));
            oc[p] = pack2(fmaxf(v.x, 0.f), fmaxf(v.y, 0.f));
        }
        uint4 o; o.x = oc[0]; o.y = oc[1]; o.z = oc[2]; o.w = oc[3];
        *reinterpret_cast<uint4*>(&lds[(size_t)t * 32 + ((c ^ (t & 7)) << 2)]) = o;
    }
    __syncthreads();

    // B fragments + bias-initialized accumulators
    f16x8 bf[2][4];
    #pragma unroll
    for (int ks = 0; ks < 2; ++ks)
        #pragma unroll
        for (int ni = 0; ni < 4; ++ni) {
            U4F u;
            u.u = *reinterpret_cast<const uint4*>(w2f + (size_t)((ks * 4 + ni) * 64 + t) * 4);
            bf[ks][ni] = u.h;
        }
    f32x4 acc[4][4];
    #pragma unroll
    for (int ni = 0; ni < 4; ++ni) {
        float bb = b2[ni * 16 + (t & 15)];
        #pragma unroll
        for (int mi = 0; mi < 4; ++mi) acc[mi][ni] = (f32x4){bb, bb, bb, bb};
    }

    // layer 2 GEMM: 64x64x64 = 2 K-steps x 4 M-tiles x 4 N-tiles MFMA
    #pragma unroll
    for (int ks = 0; ks < 2; ++ks) {
        #pragma unroll
        for (int mi = 0; mi < 4; ++mi) {
            int row = mi * 16 + (t & 15);
            int ch  = (ks * 4 + (t >> 4)) ^ (row & 7);   // undo A-stage swizzle
            U4F a;
            a.u = *reinterpret_cast<const uint4*>(&lds[(size_t)row * 32 + (ch << 2)]);
            #pragma unroll
            for (int ni = 0; ni < 4; ++ni)
                acc[mi][ni] = __builtin_amdgcn_mfma_f32_16x16x32_f16(
                    a.h, bf[ks][ni], acc[mi][ni], 0, 0, 0);
        }
    }
    __syncthreads();

    // restage h2 = relu(acc) as linear f16 [64][64]
    // C layout: col = ni*16+(t&15), row = mi*16+(t>>4)*4+r  [m89-verified]
    _Float16* h2s = reinterpret_cast<_Float16*>(lds);
    #pragma unroll
    for (int mi = 0; mi < 4; ++mi) {
        #pragma unroll
        for (int r = 0; r < 4; ++r) {
            int row = mi * 16 + ((t >> 4) << 2) + r;
            #pragma unroll
            for (int ni = 0; ni < 4; ++ni)
                h2s[row * 64 + ni * 16 + (t & 15)] = (_Float16)fmaxf(acc[mi][ni][r], 0.f);
        }
    }
    __syncthreads();

    // run detection (single wave)
    bool leader = (t < nE) && (t == 0 || cis[t] != cis[t - 1]);
    unsigned long long bal = __ballot(leader);
    int nruns = __popcll(bal);
    if (leader) {
        int ord = __popcll(bal & ((1ull << t) - 1));
        runStart[ord] = t;
    }
    if (t == 0) runStart[nruns] = nE;
    __syncthreads();

    // column-parallel segmented max: lane = column
    int* aggi = reinterpret_cast<int*>(agg);
    for (int r = 0; r < nruns; ++r) {
        int s = runStart[r], e2 = runStart[r + 1];
        int c2 = cis[s];
        float m = 0.f;
        for (int k = s; k < e2; ++k)
            m = fmaxf(m, (float)h2s[k * 64 + t]);
        int addr = c2 * HH + t;
        if (s == 0 || e2 == nE) {
            if (m > 0.f) atomicMax(&aggi[addr], __float_as_int(m));
        } else {
            agg[addr] = m;
        }
    }
}

// ---------------- out MLP via dot2, in-place over d_out ---------------------
__global__ __launch_bounds__(64, 4) void out_mlp2(
    float* data,
    const unsigned* __restrict__ w3p, const float* __restrict__ b3,
    const unsigned* __restrict__ w4p, const float* __restrict__ b4, int M)
{
    __shared__ unsigned lds[64 * 32];
    int t = threadIdx.x;
    int r = blockIdx.x * 64 + t;
    if (r >= M) return;

    const float4* xr = reinterpret_cast<const float4*>(data + (size_t)r * HH);
    float4 f[16];
    #pragma unroll
    for (int i = 0; i < 16; ++i) f[i] = xr[i];

    #pragma unroll
    for (int c = 0; c < 8; ++c) {
        uint4 o;
        o.x = pack2(f[2 * c].x, f[2 * c].y);
        o.y = pack2(f[2 * c].z, f[2 * c].w);
        o.z = pack2(f[2 * c + 1].x, f[2 * c + 1].y);
        o.w = pack2(f[2 * c + 1].z, f[2 * c + 1].w);
        *reinterpret_cast<uint4*>(&lds[(size_t)t * 32 + ((c ^ (t & 7)) << 2)]) = o;
    }

    float h[64];
    dot2_layer(lds, t, w3p, b3, h);

    #pragma unroll
    for (int c = 0; c < 8; ++c) {
        uint4 o;
        o.x = pack2(fmaxf(h[8 * c + 0], 0.f), fmaxf(h[8 * c + 1], 0.f));
        o.y = pack2(fmaxf(h[8 * c + 2], 0.f), fmaxf(h[8 * c + 3], 0.f));
        o.z = pack2(fmaxf(h[8 * c + 4], 0.f), fmaxf(h[8 * c + 5], 0.f));
        o.w = pack2(fmaxf(h[8 * c + 6], 0.f), fmaxf(h[8 * c + 7], 0.f));
        *reinterpret_cast<uint4*>(&lds[(size_t)t * 32 + ((c ^ (t & 7)) << 2)]) = o;
    }

    float h2[64];
    dot2_layer(lds, t, w4p, b4, h2);

    float4* yr = reinterpret_cast<float4*>(data + (size_t)r * HH);
    #pragma unroll
    for (int c = 0; c < 16; ++c) {
        float4 o;
        o.x = fmaxf(h2[4 * c + 0], 0.f);
        o.y = fmaxf(h2[4 * c + 1], 0.f);
        o.z = fmaxf(h2[4 * c + 2], 0.f);
        o.w = fmaxf(h2[4 * c + 3], 0.f);
        yr[c] = o;
    }
}

// ================= last-resort fallback (round-2) path ======================
__global__ __launch_bounds__(1024) void scan_kernel(const int* __restrict__ counts,
                                                    int* cursor, int M) {
    const int T = 1024;
    int t = threadIdx.x;
    int C = (M + T - 1) / T;
    int lo = t * C, hi = min(lo + C, M);
    int s = 0;
    for (int i = lo; i < hi; ++i) s += counts[i];
    __shared__ int ss[T];
    ss[t] = s;
    __syncthreads();
    for (int off = 1; off < T; off <<= 1) {
        int v = (t >= off) ? ss[t - off] : 0;
        __syncthreads();
        ss[t] += v;
        __syncthreads();
    }
    int run = (t == 0) ? 0 : ss[t - 1];
    for (int i = lo; i < hi; ++i) {
        cursor[i] = run;
        run += counts[i];
    }
}

__global__ __launch_bounds__(BLK) void edge_mlp_sorted(
    const float* __restrict__ last_coors, const float* __restrict__ last_features,
    const float* __restrict__ current_coors, const int* __restrict__ edge,
    const int* __restrict__ sorted,
    const float* __restrict__ W1, const float* __restrict__ b1,
    const float* __restrict__ W2, const float* __restrict__ b2,
    float* agg, int E)
{
    __shared__ float hs[BLK][HH];
    __shared__ int cis[BLK];
    __shared__ int runStart[BLK + 1];
    __shared__ int wl[BLK / 64];
    int base = blockIdx.x * BLK, t = threadIdx.x;
    int nE = min(BLK, E - base);
    int ci = -1, li = 0;
    if (t < nE) { int es = sorted[base + t]; ci = edge[es]; li = edge[E + es]; }
    cis[t] = ci;
    if (t < nE) {
        float h1[HH];
        #pragma unroll
        for (int j = 0; j < HH; ++j) h1[j] = b1[j];
        const float4* xr = reinterpret_cast<const float4*>(last_features + (size_t)li * FIN);
        #pragma unroll 1
        for (int c = 0; c < FIN / 4; ++c) {
            float4 v = xr[c];
            const float* w = W1 + (size_t)(4 * c) * HH;
            #pragma unroll
            for (int j = 0; j < HH; ++j)
                h1[j] = fmaf(v.x, w[j], fmaf(v.y, w[HH + j],
                        fmaf(v.z, w[2 * HH + j], fmaf(v.w, w[3 * HH + j], h1[j]))));
        }
        {
            float r0 = last_coors[3 * li + 0] - current_coors[3 * ci + 0];
            float r1 = last_coors[3 * li + 1] - current_coors[3 * ci + 1];
            float r2 = last_coors[3 * li + 2] - current_coors[3 * ci + 2];
            const float* w = W1 + (size_t)64 * HH;
            #pragma unroll
            for (int j = 0; j < HH; ++j)
                h1[j] = fmaf(r0, w[j], fmaf(r1, w[HH + j], fmaf(r2, w[2 * HH + j], h1[j])));
        }
        #pragma unroll
        for (int c = 0; c < HH / 4; ++c) {
            float4 v;
            v.x = fmaxf(h1[4 * c + 0], 0.f); v.y = fmaxf(h1[4 * c + 1], 0.f);
            v.z = fmaxf(h1[4 * c + 2], 0.f); v.w = fmaxf(h1[4 * c + 3], 0.f);
            int cc = (c + t) & 15;
            *reinterpret_cast<float4*>(&hs[t][cc * 4]) = v;
        }
        float h2[HH];
        #pragma unroll
        for (int j = 0; j < HH; ++j) h2[j] = b2[j];
        #pragma unroll 1
        for (int c = 0; c < HH / 4; ++c) {
            int cc = (c + t) & 15;
            float4 v = *reinterpret_cast<const float4*>(&hs[t][cc * 4]);
            const float* w = W2 + (size_t)(4 * c) * HH;
            #pragma unroll
            for (int j = 0; j < HH; ++j)
                h2[j] = fmaf(v.x, w[j], fmaf(v.y, w[HH + j],
                        fmaf(v.z, w[2 * HH + j], fmaf(v.w, w[3 * HH + j], h2[j]))));
        }
        #pragma unroll
        for (int c = 0; c < HH / 4; ++c) {
            float4 v;
            v.x = fmaxf(h2[4 * c + 0], 0.f); v.y = fmaxf(h2[4 * c + 1], 0.f);
            v.z = fmaxf(h2[4 * c + 2], 0.f); v.w = fmaxf(h2[4 * c + 3], 0.f);
            int cc = (c + t) & 15;
            *reinterpret_cast<float4*>(&hs[t][cc * 4]) = v;
        }
    }
    __syncthreads();
    bool leader = (t < nE) && (t == 0 || cis[t] != cis[t - 1]);
    unsigned long long bal = __ballot(leader);
    int lane = t & 63, wid = t >> 6;
    if (lane == 63) wl[wid] = __popcll(bal);
    __syncthreads();
    int nruns = wl[0] + wl[1];
    if (leader) {
        int ord = __popcll(bal & ((1ull << lane) - 1)) + (wid ? wl[0] : 0);
        runStart[ord] = t;
    }
    if (t == 0) runStart[nruns] = nE;
    __syncthreads();
    int col = t & 63, half = t >> 6;
    int* aggi = reinterpret_cast<int*>(agg);
    for (int r = half; r < nruns; r += BLK / 64) {
        int s = runStart[r], e2 = runStart[r + 1];
        int c2 = cis[s];
        float m = 0.f;
        for (int k = s; k < e2; ++k) {
            int cc = ((col >> 2) + k) & 15;
            m = fmaxf(m, hs[k][cc * 4 + (col & 3)]);
        }
        int addr = c2 * HH + col;
        if (s == 0 || e2 == nE) {
            if (m > 0.f) atomicMax(&aggi[addr], __float_as_int(m));
        } else {
            agg[addr] = m;
        }
    }
}

__global__ __launch_bounds__(BLK) void out_mlp_f32(
    float* data, const float* __restrict__ W3, const float* __restrict__ b3,
    const float* __restrict__ W4, const float* __restrict__ b4, int M)
{
    __shared__ float hsm[BLK][HH];
    int r = blockIdx.x * BLK + threadIdx.x;
    if (r >= M) return;
    int t = threadIdx.x;
    const float4* xr = reinterpret_cast<const float4*>(data + (size_t)r * HH);
    float h[HH];
    #pragma unroll
    for (int j = 0; j < HH; ++j) h[j] = b3[j];
    #pragma unroll 1
    for (int c = 0; c < HH / 4; ++c) {
        float4 v = xr[c];
        const float* w = W3 + (size_t)(4 * c) * HH;
        #pragma unroll
        for (int j = 0; j < HH; ++j)
            h[j] = fmaf(v.x, w[j], fmaf(v.y, w[HH + j],
                   fmaf(v.z, w[2 * HH + j], fmaf(v.w, w[3 * HH + j], h[j]))));
    }
    #pragma unroll
    for (int c = 0; c < HH / 4; ++c) {
        float4 v;
        v.x = fmaxf(h[4 * c + 0], 0.f); v.y = fmaxf(h[4 * c + 1], 0.f);
        v.z = fmaxf(h[4 * c + 2], 0.f); v.w = fmaxf(h[4 * c + 3], 0.f);
        int cc = (c + t) & 15;
        *reinterpret_cast<float4*>(&hsm[t][cc * 4]) = v;
    }
    float h2[HH];
    #pragma unroll
    for (int j = 0; j < HH; ++j) h2[j] = b4[j];
    #pragma unroll 1
    for (int c = 0; c < HH / 4; ++c) {
        int cc = (c + t) & 15;
        float4 v = *reinterpret_cast<const float4*>(&hsm[t][cc * 4]);
        const float* w = W4 + (size_t)(4 * c) * HH;
        #pragma unroll
        for (int j = 0; j < HH; ++j)
            h2[j] = fmaf(v.x, w[j], fmaf(v.y, w[HH + j],
                    fmaf(v.z, w[2 * HH + j], fmaf(v.w, w[3 * HH + j], h2[j]))));
    }
    float* yr = data + (size_t)r * HH;
    #pragma unroll
    for (int c = 0; c < HH / 4; ++c) {
        float4 v;
        v.x = fmaxf(h2[4 * c + 0], 0.f); v.y = fmaxf(h2[4 * c + 1], 0.f);
        v.z = fmaxf(h2[4 * c + 2], 0.f); v.w = fmaxf(h2[4 * c + 3], 0.f);
        *reinterpret_cast<float4*>(&yr[4 * c]) = v;
    }
}

extern "C" void kernel_launch(void* const* d_in, const int* in_sizes, int n_in,
                              void* d_out, int out_size, void* d_ws, size_t ws_size,
                              hipStream_t stream) {
    const float* last_coors    = (const float*)d_in[0];
    const float* last_features = (const float*)d_in[1];
    const float* current_coors = (const float*)d_in[2];
    const int*   edge          = (const int*)d_in[3];
    const float* W1 = (const float*)d_in[4];  const float* b1 = (const float*)d_in[5];
    const float* W2 = (const float*)d_in[6];  const float* b2 = (const float*)d_in[7];
    const float* W3 = (const float*)d_in[8];  const float* b3 = (const float*)d_in[9];
    const float* W4 = (const float*)d_in[10]; const float* b4 = (const float*)d_in[11];

    int E = in_sizes[3] / 2;
    int M = in_sizes[2] / 3;
    int N = in_sizes[0] / 3;

    float* agg = (float*)d_out;
    int NB = (M + 2047) / 2048;
    int NBUK = (M + CIW - 1) / CIW;

    // ws layout (u32): counts[M+1] | cursor[M+1] | bsum[1024] | bc[1024] |
    //                  wp[8192] | cl[2E] | bin[2E] | pre1[32N]
    unsigned* ws = (unsigned*)d_ws;
    size_t offCur = (size_t)(M + 1);
    size_t offBs  = (offCur + (M + 1) + 3) & ~(size_t)3;
    size_t offBc  = offBs + 1024;
    size_t offWp  = offBc + 1024;
    size_t offCl  = offWp + 4 * 2048;
    size_t offBin = offCl + 2 * (size_t)E;
    size_t offPre = offBin + 2 * (size_t)E;
    size_t needA  = (offPre + (size_t)N * 32) * 4;
    size_t needB  = (offBin + (size_t)N * 32) * 4;   // round-4 layout (no bin)

    int* counts = (int*)ws;
    int* cursor = (int*)(ws + offCur);
    int* bsum   = (int*)(ws + offBs);
    int* bc     = (int*)(ws + offBc);
    unsigned* wp = ws + offWp;
    int2* cl    = (int2*)(ws + offCl);

    if (ws_size >= needA && NB <= 1024 && NBUK <= 1024) {
        int2* bin   = (int2*)(ws + offBin);
        uint4* pre1 = (uint4*)(ws + offPre);

        zero_init<<<2048, 256, 0, stream>>>(agg, M * HH, counts, M + 1);
        pack_weights<<<32, 256, 0, stream>>>(W1, W2, W3, W4, wp);
        pre_pass<<<(N + 63) / 64, 64, 0, stream>>>(last_features, wp, b1, pre1, N);
        hist_kernel<<<(E + 255) / 256, 256, 0, stream>>>(edge, counts, E);
        scan_partial<<<NB, 256, 0, stream>>>(counts, bsum, M);
        scan_bsums<<<1, 64, 0, stream>>>(bsum, NB);
        scan_apply<<<NB, 256, 0, stream>>>(counts, bsum, cursor, bc, M);
        bin_scatter<<<(E + 255) / 256, 256, 0, stream>>>(edge, bc, bin, E);
        fine_scatter<<<NBUK, 256, 0, stream>>>(bin, cursor, cl, M, E);
        edge_mfma<<<(E + 63) / 64, 64, 0, stream>>>(last_coors, current_coors, cl, pre1,
                                                    W1, b2, wp + 2048, agg, E);
        out_mlp2<<<(M + 63) / 64, 64, 0, stream>>>(agg, wp + 4096, b3, wp + 6144, b4, M);
    } else if (ws_size >= needB && NB <= 1024) {
        // round-4 path: direct scatter2 (cursor is consumed destructively)
        uint4* pre1 = (uint4*)(ws + offBin);

        zero_init<<<2048, 256, 0, stream>>>(agg, M * HH, counts, M + 1);
        pack_weights<<<32, 256, 0, stream>>>(W1, W2, W3, W4, wp);
        pre_pass<<<(N + 63) / 64, 64, 0, stream>>>(last_features, wp, b1, pre1, N);
        hist_kernel<<<(E + 255) / 256, 256, 0, stream>>>(edge, counts, E);
        scan_partial<<<NB, 256, 0, stream>>>(counts, bsum, M);
        scan_bsums<<<1, 64, 0, stream>>>(bsum, NB);
        scan_apply<<<NB, 256, 0, stream>>>(counts, bsum, cursor, bc, M);
        scatter2<<<(E + 255) / 256, 256, 0, stream>>>(edge, cursor, cl, E);
        edge_mfma<<<(E + 63) / 64, 64, 0, stream>>>(last_coors, current_coors, cl, pre1,
                                                    W1, b2, wp + 2048, agg, E);
        out_mlp2<<<(M + 63) / 64, 64, 0, stream>>>(agg, wp + 4096, b3, wp + 6144, b4, M);
    } else {
        // last resort: round-2 path (counts | cursor | sorted[E])
        int* sorted = (int*)(ws + offCur + (M + 1));
        zero_init<<<2048, 256, 0, stream>>>(agg, M * HH, counts, M + 1);
        hist_kernel<<<(E + 255) / 256, 256, 0, stream>>>(edge, counts, E);
        scan_kernel<<<1, 1024, 0, stream>>>(counts, cursor, M);
        scatter_kernel<<<(E + 255) / 256, 256, 0, stream>>>(edge, cursor, sorted, E);
        edge_mlp_sorted<<<(E + BLK - 1) / BLK, BLK, 0, stream>>>(
            last_coors, last_features, current_coors, edge, sorted,
            W1, b1, W2, b2, agg, E);
        out_mlp_f32<<<(M + BLK - 1) / BLK, BLK, 0, stream>>>(agg, W3, b3, W4, b4, M);
    }
}

// Round 6
// 262.537 us; speedup vs baseline: 2.3495x; 2.3495x over previous
//
#include <hip/hip_runtime.h>
#include <hip/hip_fp16.h>

#define FIN 64
#define HH 64
#define BLK 128
#define CIW 16       // ci values per bucket (fused kernel owns CIW output rows)
#define T1 16384     // edges per phase-1 block

typedef _Float16 h2v __attribute__((ext_vector_type(2)));
typedef _Float16 f16x8 __attribute__((ext_vector_type(8)));
typedef float f32x4 __attribute__((ext_vector_type(4)));
union U4F { uint4 u; f16x8 h; };

__device__ __forceinline__ unsigned pack2(float x, float y) {
    __half2 h = __floats2half2_rn(x, y);     // .x -> low 16 bits
    union { __half2 h; unsigned u; } z; z.h = h;
    return z.u;
}
__device__ __forceinline__ float2 unpack2(unsigned u) {
    union { unsigned u; __half2 h; } z; z.u = u;
    return __half22float2(z.h);
}
__device__ __forceinline__ float fdot2f(unsigned a, unsigned b, float c) {
#if __has_builtin(__builtin_amdgcn_fdot2)
    union { unsigned u; h2v h; } za, zb; za.u = a; zb.u = b;
    return __builtin_amdgcn_fdot2(za.h, zb.h, c, false);
#else
    float2 fa = unpack2(a), fb = unpack2(b);
    return fmaf(fa.x, fb.x, fmaf(fa.y, fb.y, c));
#endif
}

// dot2 layer over own LDS row (32 u32 = 64 f16, XOR-swizzled 16B chunks)
__device__ __forceinline__ void dot2_layer(const unsigned* lds, int t,
        const unsigned* __restrict__ wp, const float* __restrict__ bias, float* h) {
    #pragma unroll
    for (int j = 0; j < 64; ++j) h[j] = bias[j];
    #pragma unroll 1
    for (int c = 0; c < 8; ++c) {
        uint4 hp = *reinterpret_cast<const uint4*>(&lds[(size_t)t * 32 + ((c ^ (t & 7)) << 2)]);
        const unsigned* w0 = wp + (4 * c + 0) * 64;
        const unsigned* w1 = wp + (4 * c + 1) * 64;
        const unsigned* w2 = wp + (4 * c + 2) * 64;
        const unsigned* w3 = wp + (4 * c + 3) * 64;
        #pragma unroll
        for (int j = 0; j < 64; ++j) {
            float a = fdot2f(hp.x, w0[j], h[j]);
            a = fdot2f(hp.y, w1[j], a);
            a = fdot2f(hp.z, w2[j], a);
            h[j] = fdot2f(hp.w, w3[j], a);
        }
    }
}

// ---------------- init helper ------------------------------------------------
__global__ void zero_init(float* agg, int nagg, int* counts, int ncnt) {
    int i = blockIdx.x * blockDim.x + threadIdx.x;
    int stride = gridDim.x * blockDim.x;
    for (int k = i; k < nagg; k += stride) agg[k] = 0.f;
    for (int k = i; k < ncnt; k += stride) counts[k] = 0;
}

// ---- pack weights: W1/W3/W4 dot2 layout; W2 -> MFMA B-fragment layout ------
__global__ void pack_weights(const float* __restrict__ W1, const float* __restrict__ W2,
                             const float* __restrict__ W3, const float* __restrict__ W4,
                             unsigned* wp) {
    int i = blockIdx.x * blockDim.x + threadIdx.x;
    if (i >= 4 * 2048) return;
    int m = i >> 11, r = i & 2047;
    if (m == 1) {
        // B-frag for mfma_f32_16x16x32_f16: lane l, tile (ks,ni), pair p:
        // B[k0..k0+1][col], col = ni*16+(l&15), k0 = ks*32+(l>>4)*8+2p
        int tile = r >> 8;            // ks*4+ni
        int l    = (r >> 2) & 63;
        int p    = r & 3;
        int ni = tile & 3, ks = tile >> 2;
        int col = ni * 16 + (l & 15);
        int k0  = ks * 32 + ((l >> 4) << 3) + 2 * p;
        wp[i] = pack2(W2[k0 * 64 + col], W2[(k0 + 1) * 64 + col]);
    } else {
        int kk = r >> 6, j = r & 63;
        const float* W = (m == 0) ? W1 : (m == 2) ? W3 : W4;
        wp[i] = pack2(W[(2 * kk) * 64 + j], W[(2 * kk + 1) * 64 + j]);
    }
}

// ---------------- pre-pass: pre1[n] = feat[n] @ W1a + b1 (f16, 128B rows) ---
__global__ __launch_bounds__(64, 4) void pre_pass(
    const float* __restrict__ last_features,
    const unsigned* __restrict__ w1p, const float* __restrict__ b1,
    uint4* pre1, int N)
{
    __shared__ unsigned lds[64 * 32];
    int t = threadIdx.x;
    int r = blockIdx.x * 64 + t;
    if (r >= N) return;

    const float4* xr = reinterpret_cast<const float4*>(last_features + (size_t)r * FIN);
    float4 f[16];
    #pragma unroll
    for (int i = 0; i < 16; ++i) f[i] = xr[i];

    #pragma unroll
    for (int c = 0; c < 8; ++c) {
        uint4 o;
        o.x = pack2(f[2 * c].x, f[2 * c].y);
        o.y = pack2(f[2 * c].z, f[2 * c].w);
        o.z = pack2(f[2 * c + 1].x, f[2 * c + 1].y);
        o.w = pack2(f[2 * c + 1].z, f[2 * c + 1].w);
        *reinterpret_cast<uint4*>(&lds[(size_t)t * 32 + ((c ^ (t & 7)) << 2)]) = o;
    }

    float h[64];
    dot2_layer(lds, t, w1p, b1, h);   // pre-activation: NO relu

    uint4* out = pre1 + (size_t)r * 8;
    #pragma unroll
    for (int c = 0; c < 8; ++c) {
        uint4 o;
        o.x = pack2(h[8 * c + 0], h[8 * c + 1]);
        o.y = pack2(h[8 * c + 2], h[8 * c + 3]);
        o.z = pack2(h[8 * c + 4], h[8 * c + 5]);
        o.w = pack2(h[8 * c + 6], h[8 * c + 7]);
        out[c] = o;
    }
}

// ---------------- coarse binning: hist / scan / reserved scatter ------------
__global__ __launch_bounds__(256) void p1_hist(const int* __restrict__ edge,
                                               int* bcnt, int E, int NBUK) {
    extern __shared__ int lh[];                  // NBUK ints
    int b = blockIdx.x, t = threadIdx.x;
    for (int j = t; j < NBUK; j += 256) lh[j] = 0;
    __syncthreads();
    int lo = b * T1, hi = min(lo + T1, E);
    for (int e = lo + t; e < hi; e += 256) atomicAdd(&lh[edge[e] / CIW], 1);
    __syncthreads();
    for (int j = t; j < NBUK; j += 256) {
        int c = lh[j];
        if (c) atomicAdd(&bcnt[j], c);
    }
}

__global__ __launch_bounds__(1024) void scan_buckets(const int* __restrict__ bcnt,
                                                     int* bbase, int* bres,
                                                     int NBUK, int E) {
    const int T = 1024;
    int t = threadIdx.x;
    int C = (NBUK + T - 1) / T;
    int lo = t * C, hi = min(lo + C, NBUK);
    int s = 0;
    for (int i = lo; i < hi; ++i) s += bcnt[i];
    __shared__ int ss[T];
    ss[t] = s;
    __syncthreads();
    for (int off = 1; off < T; off <<= 1) {
        int v = (t >= off) ? ss[t - off] : 0;
        __syncthreads();
        ss[t] += v;
        __syncthreads();
    }
    int run = (t == 0) ? 0 : ss[t - 1];
    for (int i = lo; i < hi; ++i) {
        bbase[i] = run;
        bres[i] = run;
        run += bcnt[i];
    }
    if (t == 0) bbase[NBUK] = E;
}

// two-pass per block: LDS hist -> one global reservation per (block,bucket)
// -> direct writes into the block's OWN contiguous sub-run (same-XCD lines).
__global__ __launch_bounds__(256) void p1_scatter(const int* __restrict__ edge,
                                                  int* bres, int2* bin,
                                                  int E, int NBUK) {
    extern __shared__ int sh[];                  // lh[NBUK] | lofs[NBUK]
    int* lh = sh;
    int* lofs = sh + NBUK;
    int b = blockIdx.x, t = threadIdx.x;
    for (int j = t; j < NBUK; j += 256) lh[j] = 0;
    __syncthreads();
    int lo = b * T1, hi = min(lo + T1, E);
    for (int e = lo + t; e < hi; e += 256) atomicAdd(&lh[edge[e] / CIW], 1);
    __syncthreads();
    for (int j = t; j < NBUK; j += 256) {
        int c = lh[j];
        lofs[j] = c ? atomicAdd(&bres[j], c) : 0;
        lh[j] = 0;                               // reuse as running cursor
    }
    __syncthreads();
    for (int e = lo + t; e < hi; e += 256) {
        int ci = edge[e];
        int bk = ci / CIW;
        int p = lofs[bk] + atomicAdd(&lh[bk], 1);
        bin[p] = make_int2(ci, edge[E + e]);
    }
}

// ------ fused edge kernel: MLP (VALU+MFMA) + LDS running segmax per bucket --
__global__ __launch_bounds__(64, 2) void edge_mfma_fused(
    const float* __restrict__ last_coors,
    const float* __restrict__ current_coors,
    const int2* __restrict__ bin,
    const uint4* __restrict__ pre1,
    const float* __restrict__ W1,          // rel rows at W1 + 64*64
    const float* __restrict__ b2,
    const unsigned* __restrict__ w2f,      // W2 in B-frag layout
    const int* __restrict__ bbase,
    float* agg, int M)
{
    __shared__ unsigned lds[64 * 32];      // 8 KB: A-stage (swizzled f16) / h2 linear
    __shared__ float rmax[CIW][64];        // 4 KB running max (this block's rows)
    __shared__ int cis[64];
    int bkt = blockIdx.x, t = threadIdx.x;
    int lo = bkt * CIW;
    int start = bbase[bkt], end = bbase[bkt + 1];

    #pragma unroll
    for (int r = 0; r < CIW; ++r) rmax[r][t] = 0.f;

    // B fragments + bias (amortized over all tiles of this bucket)
    f16x8 bf[2][4];
    #pragma unroll
    for (int ks = 0; ks < 2; ++ks)
        #pragma unroll
        for (int ni = 0; ni < 4; ++ni) {
            U4F u;
            u.u = *reinterpret_cast<const uint4*>(w2f + (size_t)((ks * 4 + ni) * 64 + t) * 4);
            bf[ks][ni] = u.h;
        }
    float bb[4];
    #pragma unroll
    for (int ni = 0; ni < 4; ++ni) bb[ni] = b2[ni * 16 + (t & 15)];

    const float* rw = W1 + 64 * 64;
    _Float16* h2s = reinterpret_cast<_Float16*>(lds);

    for (int s = start; s < end; s += 64) {
        int nE = min(64, end - s);

        uint4 q[8] = {};
        float r0 = 0.f, r1 = 0.f, r2 = 0.f;
        int ci = lo;
        if (t < nE) {
            int2 e2 = bin[s + t];
            ci = e2.x;
            int li = e2.y;
            const uint4* pr = pre1 + (size_t)li * 8;
            #pragma unroll
            for (int i = 0; i < 8; ++i) q[i] = pr[i];
            r0 = last_coors[3 * li + 0] - current_coors[3 * ci + 0];
            r1 = last_coors[3 * li + 1] - current_coors[3 * ci + 1];
            r2 = last_coors[3 * li + 2] - current_coors[3 * ci + 2];
        }
        cis[t] = ci;

        // h1 = relu(pre + rel @ W1b) -> LDS A-stage, XOR-swizzled 16B chunks
        #pragma unroll
        for (int c = 0; c < 8; ++c) {
            unsigned qc[4] = {q[c].x, q[c].y, q[c].z, q[c].w};
            unsigned oc[4];
            #pragma unroll
            for (int p = 0; p < 4; ++p) {
                int j0 = 8 * c + 2 * p;
                float2 v = unpack2(qc[p]);
                v.x = fmaf(r0, rw[j0],     fmaf(r1, rw[64 + j0],     fmaf(r2, rw[128 + j0],     v.x)));
                v.y = fmaf(r0, rw[j0 + 1], fmaf(r1, rw[64 + j0 + 1], fmaf(r2, rw[128 + j0 + 1], v.y)));
                oc[p] = pack2(fmaxf(v.x, 0.f), fmaxf(v.y, 0.f));
            }
            uint4 o; o.x = oc[0]; o.y = oc[1]; o.z = oc[2]; o.w = oc[3];
            *reinterpret_cast<uint4*>(&lds[(size_t)t * 32 + ((c ^ (t & 7)) << 2)]) = o;
        }
        __syncthreads();

        f32x4 acc[4][4];
        #pragma unroll
        for (int ni = 0; ni < 4; ++ni)
            #pragma unroll
            for (int mi = 0; mi < 4; ++mi)
                acc[mi][ni] = (f32x4){bb[ni], bb[ni], bb[ni], bb[ni]};

        // layer 2 GEMM: 64x64x64 = 2 K-steps x 4 M-tiles x 4 N-tiles MFMA
        #pragma unroll
        for (int ks = 0; ks < 2; ++ks) {
            #pragma unroll
            for (int mi = 0; mi < 4; ++mi) {
                int row = mi * 16 + (t & 15);
                int ch  = (ks * 4 + (t >> 4)) ^ (row & 7);   // undo A-stage swizzle
                U4F a;
                a.u = *reinterpret_cast<const uint4*>(&lds[(size_t)row * 32 + (ch << 2)]);
                #pragma unroll
                for (int ni = 0; ni < 4; ++ni)
                    acc[mi][ni] = __builtin_amdgcn_mfma_f32_16x16x32_f16(
                        a.h, bf[ks][ni], acc[mi][ni], 0, 0, 0);
            }
        }
        __syncthreads();

        // restage h2 = relu(acc) as linear f16 [64][64]
        // C layout: col = ni*16+(t&15), row = mi*16+(t>>4)*4+r  [m89-verified]
        #pragma unroll
        for (int mi = 0; mi < 4; ++mi) {
            #pragma unroll
            for (int r = 0; r < 4; ++r) {
                int row = mi * 16 + ((t >> 4) << 2) + r;
                #pragma unroll
                for (int ni = 0; ni < 4; ++ni)
                    h2s[row * 64 + ni * 16 + (t & 15)] = (_Float16)fmaxf(acc[mi][ni][r], 0.f);
            }
        }
        __syncthreads();

        // running segmax into this block's LDS rows (lane = column)
        for (int k = 0; k < nE; ++k) {
            int row = cis[k] - lo;
            rmax[row][t] = fmaxf(rmax[row][t], (float)h2s[k * 64 + t]);
        }
        __syncthreads();   // before next tile overwrites lds/cis
    }

    // block-exclusive contiguous writeout (also covers empty buckets with 0)
    #pragma unroll
    for (int r = 0; r < CIW; ++r) {
        int gr = lo + r;
        if (gr < M) agg[(size_t)gr * 64 + t] = rmax[r][t];
    }
}

// ---------------- out MLP via dot2, in-place over d_out ---------------------
__global__ __launch_bounds__(64, 4) void out_mlp2(
    float* data,
    const unsigned* __restrict__ w3p, const float* __restrict__ b3,
    const unsigned* __restrict__ w4p, const float* __restrict__ b4, int M)
{
    __shared__ unsigned lds[64 * 32];
    int t = threadIdx.x;
    int r = blockIdx.x * 64 + t;
    if (r >= M) return;

    const float4* xr = reinterpret_cast<const float4*>(data + (size_t)r * HH);
    float4 f[16];
    #pragma unroll
    for (int i = 0; i < 16; ++i) f[i] = xr[i];

    #pragma unroll
    for (int c = 0; c < 8; ++c) {
        uint4 o;
        o.x = pack2(f[2 * c].x, f[2 * c].y);
        o.y = pack2(f[2 * c].z, f[2 * c].w);
        o.z = pack2(f[2 * c + 1].x, f[2 * c + 1].y);
        o.w = pack2(f[2 * c + 1].z, f[2 * c + 1].w);
        *reinterpret_cast<uint4*>(&lds[(size_t)t * 32 + ((c ^ (t & 7)) << 2)]) = o;
    }

    float h[64];
    dot2_layer(lds, t, w3p, b3, h);

    #pragma unroll
    for (int c = 0; c < 8; ++c) {
        uint4 o;
        o.x = pack2(fmaxf(h[8 * c + 0], 0.f), fmaxf(h[8 * c + 1], 0.f));
        o.y = pack2(fmaxf(h[8 * c + 2], 0.f), fmaxf(h[8 * c + 3], 0.f));
        o.z = pack2(fmaxf(h[8 * c + 4], 0.f), fmaxf(h[8 * c + 5], 0.f));
        o.w = pack2(fmaxf(h[8 * c + 6], 0.f), fmaxf(h[8 * c + 7], 0.f));
        *reinterpret_cast<uint4*>(&lds[(size_t)t * 32 + ((c ^ (t & 7)) << 2)]) = o;
    }

    float h2[64];
    dot2_layer(lds, t, w4p, b4, h2);

    float4* yr = reinterpret_cast<float4*>(data + (size_t)r * HH);
    #pragma unroll
    for (int c = 0; c < 16; ++c) {
        float4 o;
        o.x = fmaxf(h2[4 * c + 0], 0.f);
        o.y = fmaxf(h2[4 * c + 1], 0.f);
        o.z = fmaxf(h2[4 * c + 2], 0.f);
        o.w = fmaxf(h2[4 * c + 3], 0.f);
        yr[c] = o;
    }
}

// ================= last-resort fallback (round-2) path ======================
__global__ void hist_kernel(const int* __restrict__ edge, int* counts, int E) {
    int e = blockIdx.x * blockDim.x + threadIdx.x;
    if (e < E) atomicAdd(&counts[edge[e]], 1);
}

__global__ __launch_bounds__(1024) void scan_kernel(const int* __restrict__ counts,
                                                    int* cursor, int M) {
    const int T = 1024;
    int t = threadIdx.x;
    int C = (M + T - 1) / T;
    int lo = t * C, hi = min(lo + C, M);
    int s = 0;
    for (int i = lo; i < hi; ++i) s += counts[i];
    __shared__ int ss[T];
    ss[t] = s;
    __syncthreads();
    for (int off = 1; off < T; off <<= 1) {
        int v = (t >= off) ? ss[t - off] : 0;
        __syncthreads();
        ss[t] += v;
        __syncthreads();
    }
    int run = (t == 0) ? 0 : ss[t - 1];
    for (int i = lo; i < hi; ++i) {
        cursor[i] = run;
        run += counts[i];
    }
}

__global__ void scatter_kernel(const int* __restrict__ edge, int* cursor,
                               int* sorted, int E) {
    int e = blockIdx.x * blockDim.x + threadIdx.x;
    if (e < E) {
        int p = atomicAdd(&cursor[edge[e]], 1);
        sorted[p] = e;
    }
}

__global__ __launch_bounds__(BLK) void edge_mlp_sorted(
    const float* __restrict__ last_coors, const float* __restrict__ last_features,
    const float* __restrict__ current_coors, const int* __restrict__ edge,
    const int* __restrict__ sorted,
    const float* __restrict__ W1, const float* __restrict__ b1,
    const float* __restrict__ W2, const float* __restrict__ b2,
    float* agg, int E)
{
    __shared__ float hs[BLK][HH];
    __shared__ int cis[BLK];
    __shared__ int runStart[BLK + 1];
    __shared__ int wl[BLK / 64];
    int base = blockIdx.x * BLK, t = threadIdx.x;
    int nE = min(BLK, E - base);
    int ci = -1, li = 0;
    if (t < nE) { int es = sorted[base + t]; ci = edge[es]; li = edge[E + es]; }
    cis[t] = ci;
    if (t < nE) {
        float h1[HH];
        #pragma unroll
        for (int j = 0; j < HH; ++j) h1[j] = b1[j];
        const float4* xr = reinterpret_cast<const float4*>(last_features + (size_t)li * FIN);
        #pragma unroll 1
        for (int c = 0; c < FIN / 4; ++c) {
            float4 v = xr[c];
            const float* w = W1 + (size_t)(4 * c) * HH;
            #pragma unroll
            for (int j = 0; j < HH; ++j)
                h1[j] = fmaf(v.x, w[j], fmaf(v.y, w[HH + j],
                        fmaf(v.z, w[2 * HH + j], fmaf(v.w, w[3 * HH + j], h1[j]))));
        }
        {
            float r0 = last_coors[3 * li + 0] - current_coors[3 * ci + 0];
            float r1 = last_coors[3 * li + 1] - current_coors[3 * ci + 1];
            float r2 = last_coors[3 * li + 2] - current_coors[3 * ci + 2];
            const float* w = W1 + (size_t)64 * HH;
            #pragma unroll
            for (int j = 0; j < HH; ++j)
                h1[j] = fmaf(r0, w[j], fmaf(r1, w[HH + j], fmaf(r2, w[2 * HH + j], h1[j])));
        }
        #pragma unroll
        for (int c = 0; c < HH / 4; ++c) {
            float4 v;
            v.x = fmaxf(h1[4 * c + 0], 0.f); v.y = fmaxf(h1[4 * c + 1], 0.f);
            v.z = fmaxf(h1[4 * c + 2], 0.f); v.w = fmaxf(h1[4 * c + 3], 0.f);
            int cc = (c + t) & 15;
            *reinterpret_cast<float4*>(&hs[t][cc * 4]) = v;
        }
        float h2[HH];
        #pragma unroll
        for (int j = 0; j < HH; ++j) h2[j] = b2[j];
        #pragma unroll 1
        for (int c = 0; c < HH / 4; ++c) {
            int cc = (c + t) & 15;
            float4 v = *reinterpret_cast<const float4*>(&hs[t][cc * 4]);
            const float* w = W2 + (size_t)(4 * c) * HH;
            #pragma unroll
            for (int j = 0; j < HH; ++j)
                h2[j] = fmaf(v.x, w[j], fmaf(v.y, w[HH + j],
                        fmaf(v.z, w[2 * HH + j], fmaf(v.w, w[3 * HH + j], h2[j]))));
        }
        #pragma unroll
        for (int c = 0; c < HH / 4; ++c) {
            float4 v;
            v.x = fmaxf(h2[4 * c + 0], 0.f); v.y = fmaxf(h2[4 * c + 1], 0.f);
            v.z = fmaxf(h2[4 * c + 2], 0.f); v.w = fmaxf(h2[4 * c + 3], 0.f);
            int cc = (c + t) & 15;
            *reinterpret_cast<float4*>(&hs[t][cc * 4]) = v;
        }
    }
    __syncthreads();
    bool leader = (t < nE) && (t == 0 || cis[t] != cis[t - 1]);
    unsigned long long bal = __ballot(leader);
    int lane = t & 63, wid = t >> 6;
    if (lane == 63) wl[wid] = __popcll(bal);
    __syncthreads();
    int nruns = wl[0] + wl[1];
    if (leader) {
        int ord = __popcll(bal & ((1ull << lane) - 1)) + (wid ? wl[0] : 0);
        runStart[ord] = t;
    }
    if (t == 0) runStart[nruns] = nE;
    __syncthreads();
    int col = t & 63, half = t >> 6;
    int* aggi = reinterpret_cast<int*>(agg);
    for (int r = half; r < nruns; r += BLK / 64) {
        int s = runStart[r], e2 = runStart[r + 1];
        int c2 = cis[s];
        float m = 0.f;
        for (int k = s; k < e2; ++k) {
            int cc = ((col >> 2) + k) & 15;
            m = fmaxf(m, hs[k][cc * 4 + (col & 3)]);
        }
        int addr = c2 * HH + col;
        if (s == 0 || e2 == nE) {
            if (m > 0.f) atomicMax(&aggi[addr], __float_as_int(m));
        } else {
            agg[addr] = m;
        }
    }
}

__global__ __launch_bounds__(BLK) void out_mlp_f32(
    float* data, const float* __restrict__ W3, const float* __restrict__ b3,
    const float* __restrict__ W4, const float* __restrict__ b4, int M)
{
    __shared__ float hsm[BLK][HH];
    int r = blockIdx.x * BLK + threadIdx.x;
    if (r >= M) return;
    int t = threadIdx.x;
    const float4* xr = reinterpret_cast<const float4*>(data + (size_t)r * HH);
    float h[HH];
    #pragma unroll
    for (int j = 0; j < HH; ++j) h[j] = b3[j];
    #pragma unroll 1
    for (int c = 0; c < HH / 4; ++c) {
        float4 v = xr[c];
        const float* w = W3 + (size_t)(4 * c) * HH;
        #pragma unroll
        for (int j = 0; j < HH; ++j)
            h[j] = fmaf(v.x, w[j], fmaf(v.y, w[HH + j],
                   fmaf(v.z, w[2 * HH + j], fmaf(v.w, w[3 * HH + j], h[j]))));
    }
    #pragma unroll
    for (int c = 0; c < HH / 4; ++c) {
        float4 v;
        v.x = fmaxf(h[4 * c + 0], 0.f); v.y = fmaxf(h[4 * c + 1], 0.f);
        v.z = fmaxf(h[4 * c + 2], 0.f); v.w = fmaxf(h[4 * c + 3], 0.f);
        int cc = (c + t) & 15;
        *reinterpret_cast<float4*>(&hsm[t][cc * 4]) = v;
    }
    float h2[HH];
    #pragma unroll
    for (int j = 0; j < HH; ++j) h2[j] = b4[j];
    #pragma unroll 1
    for (int c = 0; c < HH / 4; ++c) {
        int cc = (c + t) & 15;
        float4 v = *reinterpret_cast<const float4*>(&hsm[t][cc * 4]);
        const float* w = W4 + (size_t)(4 * c) * HH;
        #pragma unroll
        for (int j = 0; j < HH; ++j)
            h2[j] = fmaf(v.x, w[j], fmaf(v.y, w[HH + j],
                    fmaf(v.z, w[2 * HH + j], fmaf(v.w, w[3 * HH + j], h2[j]))));
    }
    float* yr = data + (size_t)r * HH;
    #pragma unroll
    for (int c = 0; c < HH / 4; ++c) {
        float4 v;
        v.x = fmaxf(h2[4 * c + 0], 0.f); v.y = fmaxf(h2[4 * c + 1], 0.f);
        v.z = fmaxf(h2[4 * c + 2], 0.f); v.w = fmaxf(h2[4 * c + 3], 0.f);
        *reinterpret_cast<float4*>(&yr[4 * c]) = v;
    }
}

extern "C" void kernel_launch(void* const* d_in, const int* in_sizes, int n_in,
                              void* d_out, int out_size, void* d_ws, size_t ws_size,
                              hipStream_t stream) {
    const float* last_coors    = (const float*)d_in[0];
    const float* last_features = (const float*)d_in[1];
    const float* current_coors = (const float*)d_in[2];
    const int*   edge          = (const int*)d_in[3];
    const float* W1 = (const float*)d_in[4];  const float* b1 = (const float*)d_in[5];
    const float* W2 = (const float*)d_in[6];  const float* b2 = (const float*)d_in[7];
    const float* W3 = (const float*)d_in[8];  const float* b3 = (const float*)d_in[9];
    const float* W4 = (const float*)d_in[10]; const float* b4 = (const float*)d_in[11];

    int E = in_sizes[3] / 2;
    int M = in_sizes[2] / 3;
    int N = in_sizes[0] / 3;

    float* agg = (float*)d_out;
    int NBUK = (M + CIW - 1) / CIW;
    int NB1  = (E + T1 - 1) / T1;

    // ws layout (u32): bcnt[NBUK] | bbase[NBUK+1] | bres[NBUK] |
    //                  wp[8192] | bin[2E] | pre1[32N]
    unsigned* ws = (unsigned*)d_ws;
    size_t offBbase = (size_t)NBUK;
    size_t offBres  = offBbase + NBUK + 1;
    size_t offWp    = (offBres + NBUK + 3) & ~(size_t)3;
    size_t offBin   = offWp + 4 * 2048;
    size_t offPre   = offBin + 2 * (size_t)E;
    size_t need     = (offPre + (size_t)N * 32) * 4;

    if (ws_size >= need && NBUK <= 8192) {
        int* bcnt    = (int*)ws;
        int* bbase   = (int*)(ws + offBbase);
        int* bres    = (int*)(ws + offBres);
        unsigned* wp = ws + offWp;
        int2* bin    = (int2*)(ws + offBin);
        uint4* pre1  = (uint4*)(ws + offPre);

        zero_init<<<16, 256, 0, stream>>>(agg, 0, bcnt, NBUK);
        pack_weights<<<32, 256, 0, stream>>>(W1, W2, W3, W4, wp);
        pre_pass<<<(N + 63) / 64, 64, 0, stream>>>(last_features, wp, b1, pre1, N);
        p1_hist<<<NB1, 256, NBUK * 4, stream>>>(edge, bcnt, E, NBUK);
        scan_buckets<<<1, 1024, 0, stream>>>(bcnt, bbase, bres, NBUK, E);
        p1_scatter<<<NB1, 256, 2 * NBUK * 4, stream>>>(edge, bres, bin, E, NBUK);
        edge_mfma_fused<<<NBUK, 64, 0, stream>>>(last_coors, current_coors, bin, pre1,
                                                 W1, b2, wp + 2048, bbase, agg, M);
        out_mlp2<<<(M + 63) / 64, 64, 0, stream>>>(agg, wp + 4096, b3, wp + 6144, b4, M);
    } else {
        // fallback: round-2 path (counts | cursor | sorted[E])
        int* counts = (int*)ws;
        int* cursor = counts + (M + 1);
        int* sorted = cursor + (M + 1);
        zero_init<<<2048, 256, 0, stream>>>(agg, M * HH, counts, M + 1);
        hist_kernel<<<(E + 255) / 256, 256, 0, stream>>>(edge, counts, E);
        scan_kernel<<<1, 1024, 0, stream>>>(counts, cursor, M);
        scatter_kernel<<<(E + 255) / 256, 256, 0, stream>>>(edge, cursor, sorted, E);
        edge_mlp_sorted<<<(E + BLK - 1) / BLK, BLK, 0, stream>>>(
            last_coors, last_features, current_coors, edge, sorted,
            W1, b1, W2, b2, agg, E);
        out_mlp_f32<<<(M + BLK - 1) / BLK, BLK, 0, stream>>>(agg, W3, b3, W4, b4, M);
    }
}